// Round 6
// baseline (31.415 us; speedup 1.0000x reference)
//
#include <hip/hip_runtime.h>

// YOLOLayer: B=16, NA=3, NC=80, G=64, stride=8
// in : x[B][NA*85][64][64] f32   (channel-major)
// out: boxes[B*NA*4096][4] ++ conf[B*NA*4096] ++ cls[B*NA*4096][80]  (flat f32)
//
// r6: BARRIER-FREE wave-private pipeline. The transpose only mixes data
// within {85ch x position-range}, so each wave owns a private 85x16 tile
// (double-buffered, 10.9 KB/wave) and runs a fully independent stream:
//   stage(t+1) -> counted vmcnt -> compute(t). No s_barrier anywhere.
// vmcnt counts per tile: 6 global_load_lds (stage) + 7 stores (compute),
// uniform per wave. Mid-loop waits use vmcnt(13) = allow {7 stores of tile
// t-1 + 6 loads of tile t+1} in flight while guaranteeing tile t's loads
// landed (vmcnt retires in issue order, m135).
// Swizzle: idx(ch,p) = ch*16 + (p ^ (ch&12)) — granule-aligned XOR so the
// linear gload_lds dest works with a pre-swizzled SOURCE (rule #21).

#define NB 16
#define NA 3
#define NC 80
#define GG 4096   // 64*64
#define CH 85     // 5 + NC
#define SP 16     // positions per wave-tile
#define NGW 340   // float4 granules per wave-tile (85*4)
#define FLT 1360  // floats per tile buffer (85*16)

__device__ __forceinline__ float sigmoidf(float v) {
    return 1.0f / (1.0f + __expf(-v));
}

__global__ __launch_bounds__(256) void yolo_kernel(const float* __restrict__ x,
                                                   float* __restrict__ out) {
    __shared__ float lds[4][2][FLT];      // per-wave double buffers, 43.5 KB

    const int tid  = threadIdx.x;
    const int lane = tid & 63;
    const int wv   = tid >> 6;
    const int W    = blockIdx.x * 4 + wv; // 0..3071; wave owns 64 positions
    const int ba   = W >> 6;              // b*NA + a
    const int a    = ba % NA;
    const int base = (W & 63) << 6;       // first of 64 consecutive positions

    const float* __restrict__ xrow = x + (size_t)ba * CH * GG;

    float* __restrict__ boxesF = out;                             // [..][4]
    float* __restrict__ conf   = out + (size_t)NB * NA * GG * 4;
    float4* __restrict__ cls4  =
        reinterpret_cast<float4*>(out + (size_t)NB * NA * GG * 5);

    const float aw = (a == 0) ? 0.1f * 64 * 8 : (a == 1) ? 0.3f * 64 * 8 : 0.6f * 64 * 8;
    const float ah = (a == 0) ? 0.13f * 64 * 8 : (a == 1) ? 0.35f * 64 * 8 : 0.55f * 64 * 8;

    // ---- stage one 85x16 tile: exactly 6 global_load_lds per wave ----
    auto stage = [&](int k, int buf) {
        const float* src = xrow + (base + k * SP);
        #pragma unroll
        for (int it = 0; it < 6; ++it) {
            int g = it * 64 + lane;
            if (g < NGW) {                // it<5: all lanes; it=5: lanes 0..19
                int ch = g >> 2;          // 4 granules per channel row
                int q  = g & 3;
                int sq = q ^ ((ch >> 2) & 3);     // pre-swizzled source granule
                const float* gp = src + (size_t)ch * GG + (sq << 2);
                float* lp = &lds[wv][buf][it * 256];  // uniform; HW adds lane*16B
                __builtin_amdgcn_global_load_lds(
                    (const __attribute__((address_space(1))) void*)gp,
                    (__attribute__((address_space(3))) void*)lp,
                    16, 0, 0);
            }
        }
    };

    // ---- compute one tile: exactly 7 store instructions per wave ----
    auto compute = [&](int k, int buf) {
        const float* __restrict__ L = lds[wv][buf];
        const int s0  = base + k * SP;
        const int loc = ba * GG + s0;

        // boxes: 64 lanes = 16 positions x 4 components; conf: lanes 0..15
        {
            int p = lane >> 2, comp = lane & 3;
            float v  = L[comp * 16 + p];          // ch<4 -> XOR 0
            float e  = __expf(comp >= 2 ? v : -v);
            float sg = 1.0f / (1.0f + e);
            float gxy  = (comp == 0) ? (float)((s0 & 63) + p) : (float)(s0 >> 6);
            float anch = (comp == 2) ? aw : ah;
            float r = (comp < 2) ? (sg + gxy) * 8.0f : e * anch;
            boxesF[(size_t)loc * 4 + lane] = r;   // 256B contiguous
            if (lane < SP)
                conf[loc + lane] = sigmoidf(L[64 + (lane ^ 4)]);  // ch=4, XOR 4
        }

        // cls: 16 pos x 20 quads = 320 float4 = exactly 5 full-wave iters
        #pragma unroll
        for (int it = 0; it < 5; ++it) {
            int i  = it * 64 + lane;
            int p  = i / 20;
            int c4 = i - p * 20;
            int r0 = 5 + (c4 << 2);
            float4 v;
            v.x = sigmoidf(L[(r0 + 0) * 16 + (p ^ ((r0 + 0) & 12))]);
            v.y = sigmoidf(L[(r0 + 1) * 16 + (p ^ ((r0 + 1) & 12))]);
            v.z = sigmoidf(L[(r0 + 2) * 16 + (p ^ ((r0 + 2) & 12))]);
            v.w = sigmoidf(L[(r0 + 3) * 16 + (p ^ ((r0 + 3) & 12))]);
            cls4[(size_t)loc * 20 + i] = v;       // 1KB contiguous per wave
        }
    };

    // ---- barrier-free per-wave pipeline over 4 tiles ----
    stage(0, 0);
    stage(1, 1);
    asm volatile("s_waitcnt vmcnt(6)" ::: "memory");   // tile0 loads landed
    __builtin_amdgcn_sched_barrier(0);
    compute(0, 0);

    stage(2, 0);
    asm volatile("s_waitcnt vmcnt(13)" ::: "memory");  // tile1 landed; S0+L2 fly
    __builtin_amdgcn_sched_barrier(0);
    compute(1, 1);

    stage(3, 1);
    asm volatile("s_waitcnt vmcnt(13)" ::: "memory");  // tile2 landed; S1+L3 fly
    __builtin_amdgcn_sched_barrier(0);
    compute(2, 0);

    asm volatile("s_waitcnt vmcnt(0)" ::: "memory");   // tile3 landed
    __builtin_amdgcn_sched_barrier(0);
    compute(3, 1);
}

extern "C" void kernel_launch(void* const* d_in, const int* in_sizes, int n_in,
                              void* d_out, int out_size, void* d_ws, size_t ws_size,
                              hipStream_t stream) {
    const float* x = (const float*)d_in[0];
    float* out = (float*)d_out;
    yolo_kernel<<<dim3(768), 256, 0, stream>>>(x, out);  // 3 blocks/CU exactly
}

// Round 7
// 25.180 us; speedup vs baseline: 1.2476x; 1.2476x over previous
//
#include <hip/hip_runtime.h>

// YOLOLayer: B=16, NA=3, NC=80, G=64, stride=8
// in : x[B][NA*85][64][64] f32   (channel-major)
// out: boxes[B*NA*4096][4] ++ conf[B*NA*4096] ++ cls[B*NA*4096][80]  (flat f32)
//
// r7 = r5 (best, 25.2us) + three fixes, staging geometry untouched:
//  - uniform 7 stores/wave (boxes+conf spread across all 4 waves) so the
//    mid-loop counted wait can be vmcnt(13): previous tile's stores and next
//    tile's loads BOTH stay in flight (r5's vmcnt(6) force-drained stores).
//  - T1 XCD swizzle (768 = 8*96, bijective): each XCD reads a contiguous
//    ~8.4MB input slab -> L2-local read stream.
//  - nontemporal output stores (outputs never re-read; don't thrash L2/L3).

#define NB 16
#define NA 3
#define NC 80
#define GG 4096   // 64*64
#define CH 85     // 5 + NC
#define S  64     // spatial positions per tile
#define NG (CH * (S / 4))   // 1360 float4 granules per tile
#define GPW (NG / 4)        // 340 granules per wave

typedef float f32x4 __attribute__((ext_vector_type(4)));

__device__ __forceinline__ float sigmoidf(float v) {
    return 1.0f / (1.0f + __expf(-v));
}

// Swizzled LDS float-index for (channel, position). Row stride = 64 floats.
__device__ __forceinline__ int lidx(int ch, int p) {
    int g = (p >> 2) ^ ((ch >> 2) & 7);
    return (ch << 6) + (g << 2) + (p & 3);
}

__global__ __launch_bounds__(256) void yolo_kernel(const float* __restrict__ x,
                                                   float* __restrict__ out) {
    __shared__ float lds[2][CH * S];      // 2 x 21.25 KB -> 3 blocks/CU

    const int tid  = threadIdx.x;
    const int lane = tid & 63;
    const int wv   = tid >> 6;

    // T1: XCD-contiguous remap. Grid 768 = 8 XCD * 96 -> bijective.
    const int wg  = (blockIdx.x & 7) * 96 + (blockIdx.x >> 3);
    const int tg0 = wg * 4;               // 4 consecutive tiles per block

    float* __restrict__ boxesF = out;                             // [..][4]
    float* __restrict__ conf   = out + (size_t)NB * NA * GG * 4;
    f32x4* __restrict__ cls4   = (f32x4*)(out + (size_t)NB * NA * GG * 5);

    // ---- stage one 85x64 tile: exactly 6 global_load_lds per wave ----
    auto stage = [&](int tg, int buf) {
        const float* __restrict__ xin =
            x + (size_t)(tg >> 6) * CH * GG + (tg & 63) * S;
        #pragma unroll
        for (int it = 0; it < 6; ++it) {
            int g0 = wv * GPW + it * 64;  // wave-uniform granule base
            if (it * 64 + lane < GPW) {   // it<5: all lanes; it=5: lanes 0..19
                int g   = g0 + lane;
                int ch  = g >> 4;         // 16 granules (256B) per channel row
                int p4  = g & 15;
                int sp4 = p4 ^ ((ch >> 2) & 7);   // pre-swizzled source
                const float* gp = xin + (size_t)ch * GG + (sp4 << 2);
                float* lp = &lds[buf][g0 << 2];   // uniform; HW adds lane*16B
                __builtin_amdgcn_global_load_lds(
                    (const __attribute__((address_space(1))) void*)gp,
                    (__attribute__((address_space(3))) void*)lp,
                    16, 0, 0);
            }
        }
    };

    // ---- compute one tile: exactly 7 store instructions per wave ----
    auto compute = [&](int tg, int buf) {
        const float* __restrict__ L = lds[buf];
        const int ba  = tg >> 6;
        const int a   = ba % NA;
        const int row = tg & 63;          // s0 = row*64 -> grid_y = row
        const int loc = ba * GG + row * S;

        const float aw = (a == 0) ? 0.1f * 64 * 8
                       : (a == 1) ? 0.3f * 64 * 8 : 0.6f * 64 * 8;
        const float ah = (a == 0) ? 0.13f * 64 * 8
                       : (a == 1) ? 0.35f * 64 * 8 : 0.55f * 64 * 8;

        // boxes: wave wv -> positions wv*16..wv*16+15, lane = pos*4 + comp
        {
            int p    = wv * 16 + (lane >> 2);
            int comp = lane & 3;
            float v  = L[lidx(comp, p)];
            float e  = __expf(comp >= 2 ? v : -v);
            float sg = 1.0f / (1.0f + e);
            float gxy  = (comp == 0) ? (float)p : (float)row;
            float anch = (comp == 2) ? aw : ah;
            float r = (comp < 2) ? (sg + gxy) * 8.0f : e * anch;
            __builtin_nontemporal_store(
                r, &boxesF[((size_t)loc + wv * 16) * 4 + lane]);  // 256B/wave
            if (lane < 16) {              // conf: 16 active lanes, exec!=0
                float cv = sigmoidf(L[lidx(4, wv * 16 + lane)]);
                __builtin_nontemporal_store(cv, &conf[loc + wv * 16 + lane]);
            }
        }

        // cls: 80x64 outputs, float4 stores contiguous across lanes
        #pragma unroll
        for (int i0 = 0; i0 < 5; ++i0) {
            int i  = i0 * 256 + tid;
            int p  = i / 20;
            int c4 = i - p * 20;
            int r0 = 5 + (c4 << 2);
            f32x4 v;
            v.x = sigmoidf(L[lidx(r0 + 0, p)]);
            v.y = sigmoidf(L[lidx(r0 + 1, p)]);
            v.z = sigmoidf(L[lidx(r0 + 2, p)]);
            v.w = sigmoidf(L[lidx(r0 + 3, p)]);
            __builtin_nontemporal_store(v, &cls4[(size_t)loc * 20 + i]);
        }
    };

    // ---- pipeline, counted vmcnt (in-order queue: [loads k][stores k-1][loads k+1]) ----
    stage(tg0 + 0, 0);
    stage(tg0 + 1, 1);
    asm volatile("s_waitcnt vmcnt(6)" ::: "memory");   // tile0 landed; s1 flies
    __builtin_amdgcn_s_barrier();
    __builtin_amdgcn_sched_barrier(0);
    compute(tg0 + 0, 0);
    __builtin_amdgcn_s_barrier();         // protect buf0 before stage(2)

    stage(tg0 + 2, 0);
    asm volatile("s_waitcnt vmcnt(13)" ::: "memory");  // tile1 landed; st0+s2 fly
    __builtin_amdgcn_s_barrier();
    __builtin_amdgcn_sched_barrier(0);
    compute(tg0 + 1, 1);
    __builtin_amdgcn_s_barrier();         // protect buf1 before stage(3)

    stage(tg0 + 3, 1);
    asm volatile("s_waitcnt vmcnt(13)" ::: "memory");  // tile2 landed; st1+s3 fly
    __builtin_amdgcn_s_barrier();
    __builtin_amdgcn_sched_barrier(0);
    compute(tg0 + 2, 0);                  // no trailing barrier: no restage left

    asm volatile("s_waitcnt vmcnt(7)" ::: "memory");   // tile3 landed; st2 flies
    __builtin_amdgcn_s_barrier();
    __builtin_amdgcn_sched_barrier(0);
    compute(tg0 + 3, 1);
}

extern "C" void kernel_launch(void* const* d_in, const int* in_sizes, int n_in,
                              void* d_out, int out_size, void* d_ws, size_t ws_size,
                              hipStream_t stream) {
    const float* x = (const float*)d_in[0];
    float* out = (float*)d_out;
    yolo_kernel<<<dim3(768), 256, 0, stream>>>(x, out);  // 3 blocks/CU exactly
}

// Round 8
// 25.107 us; speedup vs baseline: 1.2513x; 1.0029x over previous
//
#include <hip/hip_runtime.h>

// YOLOLayer: B=16, NA=3, NC=80, G=64, stride=8
// in : x[B][NA*85][64][64] f32   (channel-major)
// out: boxes[B*NA*4096][4] ++ conf[B*NA*4096] ++ cls[B*NA*4096][80]  (flat f32)
//
// r8: test the DRAM-read-granularity theory. S=128 -> each channel segment is
// 512 B (vs r5's 256 B at 16 KB stride), halving DRAM page-activation
// overhead on the read stream. 512 threads, single 42.5 KB buffer ->
// 3 blocks/CU; per-tile vmcnt(0) drain is covered by cross-block overlap
// (r7 proved counted-vs-drain waits are worth ~0 here). Async global_load_lds
// staging with pre-swizzled source (rule #21), T1 XCD swizzle, nt stores.

#define NB 16
#define NA 3
#define NC 80
#define GG 4096   // 64*64
#define CH 85     // 5 + NC
#define S  128    // spatial positions per tile (2 rows)
#define NG (CH * (S / 4))   // 2720 float4 granules per tile
#define GPW (NG / 8)        // 340 granules per wave (8 waves)

typedef float f32x4 __attribute__((ext_vector_type(4)));

__device__ __forceinline__ float sigmoidf(float v) {
    return 1.0f / (1.0f + __expf(-v));
}

// Swizzled LDS float-index for (channel, position). Row stride = 128 floats.
// Granule XOR with (ch>>2)&7 spreads the cls read pattern (lanes sharing a
// position read consecutive channel-quads) across 8 bank groups.
__device__ __forceinline__ int lidx(int ch, int p) {
    int g = (p >> 2) ^ ((ch >> 2) & 7);
    return (ch << 7) + (g << 2) + (p & 3);
}

__global__ __launch_bounds__(512) void yolo_kernel(const float* __restrict__ x,
                                                   float* __restrict__ out) {
    __shared__ float lds[CH * S];         // 42.5 KB single buffer -> 3 blocks/CU

    const int tid  = threadIdx.x;
    const int lane = tid & 63;
    const int wv   = tid >> 6;

    // T1: XCD-contiguous remap. Grid 768 = 8 XCD * 96 -> bijective.
    const int wg  = (blockIdx.x & 7) * 96 + (blockIdx.x >> 3);
    const int tg0 = wg * 2;               // 2 consecutive S=128 tiles per block

    float* __restrict__ boxesF = out;                             // [..][4]
    float* __restrict__ conf   = out + (size_t)NB * NA * GG * 4;
    f32x4* __restrict__ cls4   = (f32x4*)(out + (size_t)NB * NA * GG * 5);

    // ---- stage one 85x128 tile: exactly 6 global_load_lds per wave ----
    auto stage = [&](int tg) {
        const float* __restrict__ xin =
            x + (size_t)(tg >> 5) * CH * GG + (tg & 31) * S;
        #pragma unroll
        for (int it = 0; it < 6; ++it) {
            int g0 = wv * GPW + it * 64;  // wave-uniform granule base
            if (it * 64 + lane < GPW) {   // it<5: all lanes; it=5: lanes 0..19
                int g   = g0 + lane;
                int ch  = g >> 5;         // 32 granules (512B) per channel row
                int p4  = g & 31;
                int sp4 = p4 ^ ((ch >> 2) & 7);   // pre-swizzled source
                const float* gp = xin + (size_t)ch * GG + (sp4 << 2);
                float* lp = &lds[g0 << 2];        // uniform; HW adds lane*16B
                __builtin_amdgcn_global_load_lds(
                    (const __attribute__((address_space(1))) void*)gp,
                    (__attribute__((address_space(3))) void*)lp,
                    16, 0, 0);
            }
        }
    };

    auto compute = [&](int tg) {
        const float* __restrict__ L = lds;
        const int ba   = tg >> 5;
        const int a    = ba % NA;
        const int tpos = tg & 31;         // s0 = tpos*128 (2 spatial rows)
        const int s0   = tpos * S;
        const int loc  = ba * GG + s0;

        const float aw = (a == 0) ? 0.1f * 64 * 8
                       : (a == 1) ? 0.3f * 64 * 8 : 0.6f * 64 * 8;
        const float ah = (a == 0) ? 0.13f * 64 * 8
                       : (a == 1) ? 0.35f * 64 * 8 : 0.55f * 64 * 8;

        // boxes: 512 threads = 128 positions x 4 components, 1 store each
        {
            int p    = tid >> 2;
            int comp = tid & 3;
            float v  = L[lidx(comp, p)];          // ch<4 -> no swizzle
            float e  = __expf(comp >= 2 ? v : -v);
            float sg = 1.0f / (1.0f + e);
            float gxy  = (comp == 0) ? (float)(p & 63)
                                     : (float)((s0 + p) >> 6);
            float anch = (comp == 2) ? aw : ah;
            float r = (comp < 2) ? (sg + gxy) * 8.0f : e * anch;
            __builtin_nontemporal_store(
                r, &boxesF[(size_t)(loc + p) * 4 + comp]);   // 256B/wave
        }
        // conf: first 2 waves, 1 store each
        if (tid < S)
            __builtin_nontemporal_store(sigmoidf(L[lidx(4, tid)]),
                                        &conf[loc + tid]);

        // cls: 128 pos x 20 quads = 2560 float4, 5 full-block iters
        #pragma unroll
        for (int it = 0; it < 5; ++it) {
            int i  = it * 512 + tid;
            int p  = i / 20;
            int c4 = i - p * 20;
            int r0 = 5 + (c4 << 2);
            f32x4 v;
            v.x = sigmoidf(L[lidx(r0 + 0, p)]);
            v.y = sigmoidf(L[lidx(r0 + 1, p)]);
            v.z = sigmoidf(L[lidx(r0 + 2, p)]);
            v.w = sigmoidf(L[lidx(r0 + 3, p)]);
            __builtin_nontemporal_store(v, &cls4[(size_t)loc * 20 + i]);
        }
    };

    // ---- 2 tiles, single buffer; drains covered by 3-blocks/CU overlap ----
    stage(tg0);
    asm volatile("s_waitcnt vmcnt(0)" ::: "memory");
    __builtin_amdgcn_s_barrier();
    __builtin_amdgcn_sched_barrier(0);
    compute(tg0);

    __builtin_amdgcn_s_barrier();         // all reads done before restage
    stage(tg0 + 1);
    asm volatile("s_waitcnt vmcnt(0)" ::: "memory");
    __builtin_amdgcn_s_barrier();
    __builtin_amdgcn_sched_barrier(0);
    compute(tg0 + 1);
}

extern "C" void kernel_launch(void* const* d_in, const int* in_sizes, int n_in,
                              void* d_out, int out_size, void* d_ws, size_t ws_size,
                              hipStream_t stream) {
    const float* x = (const float*)d_in[0];
    float* out = (float*)d_out;
    yolo_kernel<<<dim3(768), 512, 0, stream>>>(x, out);  // 3 blocks/CU exactly
}